// Round 8
// baseline (580.605 us; speedup 1.0000x reference)
//
#include <hip/hip_runtime.h>
#include <stdint.h>

#define TPB 1024
#define HSZ 32768
#define NCH 8              // chunks per row
#define CHF4 1024          // float4 per chunk (16 KB); CHF4 == TPB
#define NW (TPB / 64)      // 16 waves
#define CAP 1024           // candidate capacity (threshold bin ~40 elems for N(0,1))

// LDS-only barrier: orders LDS (lgkmcnt) but leaves global/DMA ops in flight.
#define BARRIER() do { \
    asm volatile("s_waitcnt lgkmcnt(0)" ::: "memory"); \
    __builtin_amdgcn_s_barrier(); \
} while (0)

// Full drain barrier: DMA arrivals + store acks + LDS.
#define WAIT_VM0_BARRIER() do { \
    asm volatile("s_waitcnt vmcnt(0) lgkmcnt(0)" ::: "memory"); \
    __builtin_amdgcn_s_barrier(); \
} while (0)

// order-preserving float->uint key: bigger float => bigger key
__device__ __forceinline__ uint32_t f2k(float f) {
    uint32_t u = __float_as_uint(f);
    return u ^ (0x80000000u | (uint32_t)(-(int32_t)(u >> 31)));
}
__device__ __forceinline__ float k2f(uint32_t key) {
    uint32_t u = (key & 0x80000000u) ? (key ^ 0x80000000u) : ~key;
    return __uint_as_float(u);
}

struct Sm {
    float4 row[NCH * CHF4];     // 128 KB resident row (8 recyclable chunks)
    uint32_t hist[4096];        // 16 KB
    uint32_t wtot[NW];
    uint32_t cand_key[CAP];     // 4 KB
    uint32_t cand_col[CAP];     // 4 KB
    uint32_t bin, rem, eqcnt, ncand, chunk_base;
};                              // ~152 KB (<160 KB/CU; launched OK r5/r6)

// DMA one 16 KB chunk: global -> LDS slot c, no VGPR staging.
__device__ __forceinline__ void dma_chunk(const float* __restrict__ xrow, Sm& sm,
                                          int c, int t) {
    const uint32_t* g = (const uint32_t*)xrow + (size_t)c * (CHF4 * 4) + (size_t)t * 4;
    uint32_t* l = (uint32_t*)(sm.row + c * CHF4 + t);
    __builtin_amdgcn_global_load_lds(
        (const __attribute__((address_space(1))) uint32_t*)g,
        (__attribute__((address_space(3))) uint32_t*)l,
        16, 0, 0);
}

// Suffix-select over hist[4096] (descending bins = larger values).
__device__ __forceinline__ void select4096(Sm& sm, uint32_t need, int t) {
    const int lane = t & 63, wid = t >> 6;
    uint32_t b[4], pt = 0;
#pragma unroll
    for (int jj = 0; jj < 4; ++jj) { b[jj] = sm.hist[t * 4 + jj]; pt += b[jj]; }
    uint32_t pre = pt;  // wave suffix-inclusive scan
#pragma unroll
    for (int off = 1; off < 64; off <<= 1) {
        uint32_t n = (uint32_t)__shfl_down((int)pre, off, 64);
        if (lane + off < 64) pre += n;
    }
    if (lane == 0) sm.wtot[wid] = pre;
    BARRIER();
    uint32_t wsuf = 0;
    for (int w = wid + 1; w < NW; ++w) wsuf += sm.wtot[w];
    const uint32_t Sincl = pre + wsuf;
    const uint32_t Sexcl = Sincl - pt;
    if (Sexcl < need && Sincl >= need) {
        uint32_t run = Sexcl;
#pragma unroll
        for (int jj = 3; jj >= 0; --jj) {
            if (run + b[jj] >= need) { sm.bin = (uint32_t)(t * 4 + jj); sm.rem = need - run; break; }
            run += b[jj];
        }
    }
    BARRIER();
}

// Same over hist[256]; also reports count of the selected bin.
__device__ __forceinline__ void select256(Sm& sm, uint32_t need, int t) {
    const int lane = t & 63, wid = t >> 6;
    uint32_t pt = (t < 256) ? sm.hist[t] : 0u;
    uint32_t pre = pt;
#pragma unroll
    for (int off = 1; off < 64; off <<= 1) {
        uint32_t n = (uint32_t)__shfl_down((int)pre, off, 64);
        if (lane + off < 64) pre += n;
    }
    if (lane == 0) sm.wtot[wid] = pre;
    BARRIER();
    uint32_t wsuf = 0;
    for (int w = wid + 1; w < NW; ++w) wsuf += sm.wtot[w];
    const uint32_t Sincl = pre + wsuf;
    const uint32_t Sexcl = Sincl - pt;
    if (t < 256 && Sexcl < need && Sincl >= need) {
        sm.bin = (uint32_t)t; sm.rem = need - Sexcl; sm.eqcnt = pt;
    }
    BARRIER();
}

// Process row resident in sm.row. Phase B does the FINAL streaming write
// (provisional zeros in bin B1) and recycles each slot for next-row DMA
// immediately; refine + scatter-fix touch only the candidate list.
__device__ __forceinline__ void process_row(const float* __restrict__ xcur,
                                            float* __restrict__ outr,
                                            const float* __restrict__ xnext,
                                            uint32_t k, Sm& sm, int t) {
    float4* outr4 = reinterpret_cast<float4*>(outr);

    // ===== phase A: level-1 histogram (key bits [31:20]) from LDS =====
#pragma unroll
    for (int i = 0; i < 4096 / TPB; ++i) sm.hist[i * TPB + t] = 0u;
    if (t == 0) sm.ncand = 0u;
    BARRIER();
#pragma unroll
    for (int c = 0; c < NCH; ++c) {
        float4 v = sm.row[c * CHF4 + t];
        atomicAdd(&sm.hist[f2k(v.x) >> 20], 1u);
        atomicAdd(&sm.hist[f2k(v.y) >> 20], 1u);
        atomicAdd(&sm.hist[f2k(v.z) >> 20], 1u);
        atomicAdd(&sm.hist[f2k(v.w) >> 20], 1u);
    }
    BARRIER();
    select4096(sm, k, t);
    const uint32_t B1 = sm.bin;
    const uint32_t need2 = sm.rem;

    // ===== phase B: final streaming write + compact; recycle slot -> DMA =====
#pragma unroll
    for (int c = 0; c < NCH; ++c) {
        float4 v = sm.row[c * CHF4 + t];
        float vals[4] = { v.x, v.y, v.z, v.w };
        float ov[4];
#pragma unroll
        for (int e = 0; e < 4; ++e) {
            uint32_t key = f2k(vals[e]);
            uint32_t b = key >> 20;
            ov[e] = (b > B1) ? vals[e] : 0.0f;
            if (b == B1) {
                uint32_t pos = atomicAdd(&sm.ncand, 1u);
                if (pos < CAP) {
                    sm.cand_key[pos] = key;
                    sm.cand_col[pos] = (uint32_t)((c * CHF4 + t) * 4 + e);
                }
            }
        }
        BARRIER();                              // all waves done with slot c
        if (xnext) dma_chunk(xnext, sm, c, t);  // re-target slot c (async)
        float4 o; o.x = ov[0]; o.y = ov[1]; o.z = ov[2]; o.w = ov[3];
        outr4[c * CHF4 + t] = o;                // final (provisional for bin B1)
    }
    BARRIER();
    const uint32_t C = sm.ncand;

    if (C <= CAP) {
        // ===== refine among C candidates (LDS only; row slots already recycled) =====
#pragma unroll
        for (int i = 0; i < 4096 / TPB; ++i) sm.hist[i * TPB + t] = 0u;
        BARRIER();
        for (uint32_t i = t; i < C; i += TPB)
            atomicAdd(&sm.hist[(sm.cand_key[i] >> 8) & 0xFFFu], 1u);
        BARRIER();
        select4096(sm, need2, t);
        const uint32_t B2 = sm.bin;
        const uint32_t need3 = sm.rem;

        if (t < 256) sm.hist[t] = 0u;
        BARRIER();
        const uint32_t pref = (B1 << 12) | B2;
        for (uint32_t i = t; i < C; i += TPB)
            if ((sm.cand_key[i] >> 8) == pref) atomicAdd(&sm.hist[sm.cand_key[i] & 0xFFu], 1u);
        BARRIER();
        select256(sm, need3, t);
        const uint32_t K = (pref << 8) | sm.bin;
        const uint32_t eqneed = sm.rem;
        const uint32_t eqcnt = sm.eqcnt;

        // ===== scatter-fix: provisional stores must be L2-visible first; the
        // vmcnt(0) also completes next-row DMA (mandatory wait anyway) =====
        WAIT_VM0_BARRIER();
        if (eqcnt == eqneed) {
            for (uint32_t i = t; i < C; i += TPB) {
                uint32_t key = sm.cand_key[i];
                if (key >= K) outr[sm.cand_col[i]] = k2f(key);
            }
        } else {
            for (uint32_t i = t; i < C; i += TPB) {
                uint32_t key = sm.cand_key[i];
                if (key > K) {
                    outr[sm.cand_col[i]] = k2f(key);
                } else if (key == K) {
                    uint32_t rank = 0, col = sm.cand_col[i];
                    for (uint32_t m = 0; m < C; ++m)
                        if (sm.cand_key[m] == K && sm.cand_col[m] < col) ++rank;
                    if (rank < eqneed) outr[sm.cand_col[i]] = k2f(key);
                }
            }
        }
    } else {
        // ===== fallback: candidate overflow (never for Gaussian data).
        // Row slots hold next row already; re-read this row from GLOBAL
        // (input immutable) and rewrite the whole output exactly. =====
        const float4* xr4 = reinterpret_cast<const float4*>(xcur);
#pragma unroll
        for (int i = 0; i < 4096 / TPB; ++i) sm.hist[i * TPB + t] = 0u;
        BARRIER();
        for (int c = 0; c < NCH; ++c) {
            float4 v = xr4[c * CHF4 + t];
            float vals[4] = { v.x, v.y, v.z, v.w };
#pragma unroll
            for (int e = 0; e < 4; ++e) {
                uint32_t key = f2k(vals[e]);
                if ((key >> 20) == B1) atomicAdd(&sm.hist[(key >> 8) & 0xFFFu], 1u);
            }
        }
        BARRIER();
        select4096(sm, need2, t);
        const uint32_t B2 = sm.bin;
        const uint32_t need3 = sm.rem;

        if (t < 256) sm.hist[t] = 0u;
        BARRIER();
        const uint32_t pref = (B1 << 12) | B2;
        for (int c = 0; c < NCH; ++c) {
            float4 v = xr4[c * CHF4 + t];
            float vals[4] = { v.x, v.y, v.z, v.w };
#pragma unroll
            for (int e = 0; e < 4; ++e) {
                uint32_t key = f2k(vals[e]);
                if ((key >> 8) == pref) atomicAdd(&sm.hist[key & 0xFFu], 1u);
            }
        }
        BARRIER();
        select256(sm, need3, t);
        const uint32_t K = (pref << 8) | sm.bin;
        const uint32_t eqneed = sm.rem;
        const uint32_t eqcnt = sm.eqcnt;

        WAIT_VM0_BARRIER();  // provisional stores visible before full rewrite
        if (eqcnt == eqneed) {
            for (int c = 0; c < NCH; ++c) {
                float4 v = xr4[c * CHF4 + t];
                float ov[4] = {
                    (f2k(v.x) >= K) ? v.x : 0.0f, (f2k(v.y) >= K) ? v.y : 0.0f,
                    (f2k(v.z) >= K) ? v.z : 0.0f, (f2k(v.w) >= K) ? v.w : 0.0f };
                float4 o; o.x = ov[0]; o.y = ov[1]; o.z = ov[2]; o.w = ov[3];
                outr4[c * CHF4 + t] = o;
            }
        } else {
            // ordered selection among ==K by lowest column, chunk-by-chunk
            if (t == 0) sm.chunk_base = 0u;
            BARRIER();
            const int lane = t & 63;
            const int wid = t >> 6;
            for (int c = 0; c < NCH; ++c) {
                float4 v = xr4[c * CHF4 + t];
                float vals[4] = { v.x, v.y, v.z, v.w };
                uint32_t keys[4];
                uint32_t e0 = 0;
#pragma unroll
                for (int e = 0; e < 4; ++e) { keys[e] = f2k(vals[e]); e0 += (keys[e] == K) ? 1u : 0u; }
                uint32_t pre = e0;
                for (int off = 1; off < 64; off <<= 1) {
                    uint32_t n = (uint32_t)__shfl_up((int)pre, off, 64);
                    if (lane >= off) pre += n;
                }
                if (lane == 63) sm.wtot[wid] = pre;
                BARRIER();
                uint32_t before = sm.chunk_base + (pre - e0);
                for (int w = 0; w < wid; ++w) before += sm.wtot[w];
                float ov[4];
#pragma unroll
                for (int e = 0; e < 4; ++e) {
                    bool take = keys[e] > K;
                    if (keys[e] == K) { take = (before < eqneed); ++before; }
                    ov[e] = take ? vals[e] : 0.0f;
                }
                float4 o; o.x = ov[0]; o.y = ov[1]; o.z = ov[2]; o.w = ov[3];
                outr4[c * CHF4 + t] = o;
                BARRIER();
                if (t == 0) {
                    uint32_t s2 = sm.chunk_base;
#pragma unroll
                    for (int w = 0; w < NW; ++w) s2 += sm.wtot[w];
                    sm.chunk_base = s2;
                }
                BARRIER();
            }
        }
    }
}

__global__ __launch_bounds__(TPB) void topk_scatter_kernel(
    const float* __restrict__ x,
    const int* __restrict__ kp,
    float* __restrict__ out,
    int nrows)
{
    __shared__ Sm sm;
    const int t = threadIdx.x;
    const uint32_t k = (uint32_t)kp[0];
    const int gs = (int)gridDim.x;

    if (k == 0u || k >= (uint32_t)HSZ) {  // degenerate: all zeros or identity
        for (int r = (int)blockIdx.x; r < nrows; r += gs) {
            const float4* xr4 = reinterpret_cast<const float4*>(x + (size_t)r * HSZ);
            float4* outr4 = reinterpret_cast<float4*>(out + (size_t)r * HSZ);
#pragma unroll
            for (int c = 0; c < NCH; ++c) {
                float4 o;
                if (k == 0u) { o.x = o.y = o.z = o.w = 0.0f; }
                else o = xr4[c * CHF4 + t];
                outr4[c * CHF4 + t] = o;
            }
        }
        return;
    }

    int r = (int)blockIdx.x;
    if (r >= nrows) return;

    // prologue: DMA all chunks of the first row (no VGPR staging at all)
#pragma unroll
    for (int c = 0; c < NCH; ++c) dma_chunk(x + (size_t)r * HSZ, sm, c, t);

    for (;;) {
        WAIT_VM0_BARRIER();   // row r fully in LDS (nearly free after 1st row:
                              // scatter's vmcnt(0) already drained the DMA)
        const int rn = r + gs;
        const float* xnext = (rn < nrows) ? (x + (size_t)rn * HSZ) : nullptr;
        process_row(x + (size_t)r * HSZ, out + (size_t)r * HSZ, xnext, k, sm, t);
        if (rn >= nrows) break;
        r = rn;
    }
}

extern "C" void kernel_launch(void* const* d_in, const int* in_sizes, int n_in,
                              void* d_out, int out_size, void* d_ws, size_t ws_size,
                              hipStream_t stream) {
    const float* x = (const float*)d_in[0];
    const int* kp = (const int*)d_in[1];
    float* out = (float*)d_out;
    const int total = in_sizes[0];
    const int rows = total / HSZ;        // 8192
    int grid = rows < 256 ? rows : 256;  // 1 persistent block per CU (LDS-bound)
    topk_scatter_kernel<<<grid, TPB, 0, stream>>>(x, kp, out, rows);
}